// Round 7
// baseline (176.896 us; speedup 1.0000x reference)
//
#include <hip/hip_runtime.h>

// ---------------- problem constants ----------------
#define FIN   256
#define F1    128
#define F2    64

typedef _Float16 f16x8 __attribute__((ext_vector_type(8)));
typedef _Float16 f16x4 __attribute__((ext_vector_type(4)));
typedef float    f32x4 __attribute__((ext_vector_type(4)));

// Buckets: 128 dst nodes per bucket (dst>>7). For N=50000 -> 391 buckets (<512).
#define BUCKET_SHIFT 7
#define BUCKET_W     128
#define MAXBUCK      512
#define CHUNK        2048   // edges per block in bucket passes

// ---------------- bucket histogram ----------------
__global__ __launch_bounds__(256) void bucket_hist(const int* __restrict__ dst,
                                                   int* __restrict__ bhist, int E) {
    __shared__ int h[MAXBUCK];
    for (int i = threadIdx.x; i < MAXBUCK; i += 256) h[i] = 0;
    __syncthreads();
    int base = blockIdx.x * CHUNK;
#pragma unroll
    for (int i = 0; i < CHUNK / 256; ++i) {
        int e = base + i * 256 + threadIdx.x;
        if (e < E) atomicAdd(&h[dst[e] >> BUCKET_SHIFT], 1);
    }
    __syncthreads();
    for (int i = threadIdx.x; i < MAXBUCK; i += 256)
        if (h[i]) atomicAdd(&bhist[i], h[i]);
}

// ---------------- scan buckets (1 block, 512 threads) ----------------
__global__ __launch_bounds__(512) void scan_bucket(const int* __restrict__ bhist,
                                                   int* __restrict__ bbase,
                                                   int* __restrict__ bcur_pad,
                                                   int nbuck, int E) {
    __shared__ int buf[2][512];
    int t = threadIdx.x;
    int v = (t < nbuck) ? bhist[t] : 0;
    buf[0][t] = v;
    __syncthreads();
    int cur = 0;
    for (int off = 1; off < 512; off <<= 1) {
        int x = buf[cur][t];
        if (t >= off) x += buf[cur][t - off];
        buf[cur ^ 1][t] = x;
        cur ^= 1;
        __syncthreads();
    }
    int excl = (t == 0) ? 0 : buf[cur][t - 1];
    if (t < nbuck) {
        bbase[t] = excl;
        bcur_pad[t * 16] = excl;      // 64B-padded cursor (atomic target)
    }
    if (t == 0) bbase[nbuck] = E;
}

// ---------------- partition edges into bucket-segmented ebuf ----------------
__global__ __launch_bounds__(256) void bucket_fill(const int* __restrict__ src,
                                                   const int* __restrict__ dst,
                                                   int* __restrict__ bcur_pad,
                                                   uint2* __restrict__ ebuf, int E) {
    __shared__ int h[MAXBUCK];
    __shared__ int base[MAXBUCK];
    for (int i = threadIdx.x; i < MAXBUCK; i += 256) h[i] = 0;
    __syncthreads();
    int cbase = blockIdx.x * CHUNK;
#pragma unroll
    for (int i = 0; i < CHUNK / 256; ++i) {
        int e = cbase + i * 256 + threadIdx.x;
        if (e < E) atomicAdd(&h[dst[e] >> BUCKET_SHIFT], 1);
    }
    __syncthreads();
    for (int i = threadIdx.x; i < MAXBUCK; i += 256) {
        int c = h[i];
        base[i] = c ? atomicAdd(&bcur_pad[i * 16], c) : 0;
        h[i] = 0;
    }
    __syncthreads();
#pragma unroll
    for (int i = 0; i < CHUNK / 256; ++i) {
        int e = cbase + i * 256 + threadIdx.x;
        if (e < E) {
            int d = dst[e], b = d >> BUCKET_SHIFT;
            int r = atomicAdd(&h[b], 1);
            ebuf[base[b] + r] = make_uint2((unsigned)src[e], (unsigned)d);
        }
    }
}

// ---------------- per-bucket degree count (LDS only) ----------------
__global__ __launch_bounds__(256) void deg_bucket(const uint2* __restrict__ ebuf,
                                                  const int* __restrict__ bbase,
                                                  int* __restrict__ deg, int n) {
    __shared__ int cnt[BUCKET_W];
    int k = blockIdx.x;
    if (threadIdx.x < BUCKET_W) cnt[threadIdx.x] = 0;
    __syncthreads();
    int beg = bbase[k], end = bbase[k + 1];
    for (int e = beg + threadIdx.x; e < end; e += 256)
        atomicAdd(&cnt[ebuf[e].y & (BUCKET_W - 1)], 1);
    __syncthreads();
    if (threadIdx.x < BUCKET_W) {
        int node = (k << BUCKET_SHIFT) + threadIdx.x;
        if (node < n) deg[node] = cnt[threadIdx.x];
    }
}

// ---------------- hierarchical scan over deg -> rowptr, dinv ----------------
__global__ __launch_bounds__(256) void block_sum(const int* __restrict__ deg,
                                                 int* __restrict__ bsum, int n) {
    int t = threadIdx.x;
    int base = blockIdx.x * 1024 + t * 4;
    int s = 0;
    if (base + 3 < n) {
        int4 v = *(const int4*)&deg[base];
        s = v.x + v.y + v.z + v.w;
    } else {
        for (int i = 0; i < 4; ++i)
            if (base + i < n) s += deg[base + i];
    }
#pragma unroll
    for (int off = 32; off > 0; off >>= 1) s += __shfl_down(s, off, 64);
    __shared__ int ws[4];
    if ((t & 63) == 0) ws[t >> 6] = s;
    __syncthreads();
    if (t == 0) bsum[blockIdx.x] = ws[0] + ws[1] + ws[2] + ws[3];
}

__global__ void scan_bsums(int* __restrict__ bsum, int nb) {
    if (threadIdx.x == 0) {
        int run = 0;
        for (int i = 0; i < nb; ++i) {
            int v = bsum[i];
            bsum[i] = run;
            run += v;
        }
    }
}

__global__ __launch_bounds__(256) void scan_final(const int* __restrict__ deg,
                                                  const int* __restrict__ bsum,
                                                  int* __restrict__ rowptr,
                                                  float* __restrict__ dinv,
                                                  int n, int E) {
    __shared__ int buf[2][256];
    int t = threadIdx.x;
    int base = blockIdx.x * 1024 + t * 4;
    int d[4] = {0, 0, 0, 0};
    if (base + 3 < n) {
        int4 v = *(const int4*)&deg[base];
        d[0] = v.x; d[1] = v.y; d[2] = v.z; d[3] = v.w;
    } else {
        for (int i = 0; i < 4; ++i)
            if (base + i < n) d[i] = deg[base + i];
    }
    int tsum = d[0] + d[1] + d[2] + d[3];
    buf[0][t] = tsum;
    __syncthreads();
    int cur = 0;
    for (int off = 1; off < 256; off <<= 1) {
        int v = buf[cur][t];
        if (t >= off) v += buf[cur][t - off];
        buf[cur ^ 1][t] = v;
        cur ^= 1;
        __syncthreads();
    }
    int run = bsum[blockIdx.x] + ((t == 0) ? 0 : buf[cur][t - 1]);
#pragma unroll
    for (int i = 0; i < 4; ++i) {
        int idx = base + i;
        if (idx < n) {
            rowptr[idx] = run;
            dinv[idx]   = rsqrtf((float)(d[i] + 1));  // +1 self loop
            run += d[i];
        }
    }
    if (blockIdx.x == 0 && t == 0) rowptr[n] = E;
}

// ---------------- per-bucket CSR fill (one block owns one csr window) -------
__global__ __launch_bounds__(256) void csr_fill_bucket(const uint2* __restrict__ ebuf,
                                                       const int* __restrict__ bbase,
                                                       const int* __restrict__ rowptr,
                                                       int* __restrict__ csr, int n) {
    __shared__ int lcur[BUCKET_W];
    int k = blockIdx.x;
    if (threadIdx.x < BUCKET_W) {
        int node = (k << BUCKET_SHIFT) + threadIdx.x;
        lcur[threadIdx.x] = (node < n) ? rowptr[node] : 0;
    }
    __syncthreads();
    int beg = bbase[k], end = bbase[k + 1];
    for (int e = beg + threadIdx.x; e < end; e += 256) {
        uint2 ed = ebuf[e];
        int pos = atomicAdd(&lcur[ed.y & (BUCKET_W - 1)], 1);
        csr[pos] = (int)ed.x;
    }
}

// ---------------- W -> W^T f16 conversion ----------------
__global__ void cvt_wt(const float* __restrict__ W, _Float16* __restrict__ WT,
                       int K, int Nn) {
    int idx = blockIdx.x * blockDim.x + threadIdx.x;
    if (idx < K * Nn) {
        int k = idx / Nn, n = idx % Nn;
        WT[(size_t)n * K + k] = (_Float16)W[idx];
    }
}

// ---------------- f16 MFMA GEMM, f16 out, reg-prefetch double-buffered A ----
// Ch[M][BN]_f16 = dinv[row] * (A[M][K]_f32 @ W[K][BN]); WT is W^T f16 [BN][K].
// T14 async-STAGE split: prefetch next A-tile into regs right after the first
// barrier so its latency hides under B-loads + MFMA + barrier of this tile.
template <int BN, int K>
__global__ __launch_bounds__(256) void gemm_mfma(const float* __restrict__ A,
                                                 const _Float16* __restrict__ WT,
                                                 const float* __restrict__ dinv,
                                                 _Float16* __restrict__ Ch, int M) {
    constexpr int NB = BN / 16;
    __shared__ _Float16 As[64][72];

    int tid  = threadIdx.x;
    int wave = tid >> 6, lane = tid & 63;
    int col  = lane & 15, kg = lane >> 4;
    int row0 = blockIdx.x * 64;

    // per-thread staging coords (fixed across iterations)
    int sr[4], sc4[4], sgr[4];
#pragma unroll
    for (int l = 0; l < 4; ++l) {
        int f = l * 256 + tid;
        sr[l]  = f >> 4;
        sc4[l] = f & 15;
        sgr[l] = row0 + sr[l];
    }

    f32x4 acc[NB];
#pragma unroll
    for (int j = 0; j < NB; ++j) acc[j] = (f32x4){0.f, 0.f, 0.f, 0.f};

    // prefetch tile 0
    float4 pf[4];
#pragma unroll
    for (int l = 0; l < 4; ++l) {
        pf[l] = make_float4(0.f, 0.f, 0.f, 0.f);
        if (sgr[l] < M) pf[l] = *(const float4*)&A[(size_t)sgr[l] * K + sc4[l] * 4];
    }

    for (int k0 = 0; k0 < K; k0 += 64) {
        // drain prefetched regs -> LDS (f16)
#pragma unroll
        for (int l = 0; l < 4; ++l) {
            f16x4 h;
            h[0] = (_Float16)pf[l].x; h[1] = (_Float16)pf[l].y;
            h[2] = (_Float16)pf[l].z; h[3] = (_Float16)pf[l].w;
            *(f16x4*)&As[sr[l]][sc4[l] * 4] = h;
        }
        __syncthreads();
        // issue next tile's prefetch BEFORE the MFMA cluster
        if (k0 + 64 < K) {
#pragma unroll
            for (int l = 0; l < 4; ++l) {
                pf[l] = make_float4(0.f, 0.f, 0.f, 0.f);
                if (sgr[l] < M)
                    pf[l] = *(const float4*)&A[(size_t)sgr[l] * K + (k0 + 64) + sc4[l] * 4];
            }
        }
        // compute on current tile (B from global, L2-resident)
#pragma unroll
        for (int kk = 0; kk < 2; ++kk) {
            f16x8 a = *(const f16x8*)&As[wave * 16 + col][kk * 32 + kg * 8];
#pragma unroll
            for (int j = 0; j < NB; ++j) {
                f16x8 b = *(const f16x8*)&WT[(size_t)(j * 16 + col) * K + k0 + kk * 32 + kg * 8];
                acc[j] = __builtin_amdgcn_mfma_f32_16x16x32_f16(a, b, acc[j], 0, 0, 0);
            }
        }
        __syncthreads();
    }
    int rbase = row0 + wave * 16 + kg * 4;
#pragma unroll
    for (int r = 0; r < 4; ++r) {
        int m = rbase + r;
        if (m < M) {
            float dv = dinv[m];
#pragma unroll
            for (int j = 0; j < NB; ++j)
                Ch[(size_t)m * BN + j * 16 + col] = (_Float16)(dv * acc[j][r]);
        }
    }
}

// ---------------- gather aggregation: f16 rows, f32 accumulate ----------------
template <int F, bool RELU>
__global__ __launch_bounds__(256) void aggregate(const _Float16* __restrict__ Hs,
                                                 const int* __restrict__ rowptr,
                                                 const int* __restrict__ csr,
                                                 const float* __restrict__ dinv,
                                                 const float* __restrict__ bias,
                                                 float* __restrict__ out, int n) {
    constexpr int LPG = F / 4;                  // 32 (F=128) or 16 (F=64)
    int gid = (blockIdx.x * blockDim.x + threadIdx.x) / LPG;
    int sub = threadIdx.x & (LPG - 1);
    if (gid >= n) return;
    const int col = sub * 4;

    f16x4 h = *(const f16x4*)&Hs[(size_t)gid * F + col];
    float a0 = (float)h[0], a1 = (float)h[1], a2 = (float)h[2], a3 = (float)h[3];

    int beg = rowptr[gid], end = rowptr[gid + 1];
    int e = beg;

    for (; e + 8 <= end; e += 8) {
        int s0 = csr[e + 0], s1 = csr[e + 1], s2 = csr[e + 2], s3 = csr[e + 3];
        int s4 = csr[e + 4], s5 = csr[e + 5], s6 = csr[e + 6], s7 = csr[e + 7];
        f16x4 v0 = *(const f16x4*)&Hs[(size_t)s0 * F + col];
        f16x4 v1 = *(const f16x4*)&Hs[(size_t)s1 * F + col];
        f16x4 v2 = *(const f16x4*)&Hs[(size_t)s2 * F + col];
        f16x4 v3 = *(const f16x4*)&Hs[(size_t)s3 * F + col];
        f16x4 v4 = *(const f16x4*)&Hs[(size_t)s4 * F + col];
        f16x4 v5 = *(const f16x4*)&Hs[(size_t)s5 * F + col];
        f16x4 v6 = *(const f16x4*)&Hs[(size_t)s6 * F + col];
        f16x4 v7 = *(const f16x4*)&Hs[(size_t)s7 * F + col];
        a0 += (((float)v0[0] + (float)v1[0]) + ((float)v2[0] + (float)v3[0]))
            + (((float)v4[0] + (float)v5[0]) + ((float)v6[0] + (float)v7[0]));
        a1 += (((float)v0[1] + (float)v1[1]) + ((float)v2[1] + (float)v3[1]))
            + (((float)v4[1] + (float)v5[1]) + ((float)v6[1] + (float)v7[1]));
        a2 += (((float)v0[2] + (float)v1[2]) + ((float)v2[2] + (float)v3[2]))
            + (((float)v4[2] + (float)v5[2]) + ((float)v6[2] + (float)v7[2]));
        a3 += (((float)v0[3] + (float)v1[3]) + ((float)v2[3] + (float)v3[3]))
            + (((float)v4[3] + (float)v5[3]) + ((float)v6[3] + (float)v7[3]));
    }
    for (; e + 4 <= end; e += 4) {
        int s0 = csr[e + 0], s1 = csr[e + 1], s2 = csr[e + 2], s3 = csr[e + 3];
        f16x4 v0 = *(const f16x4*)&Hs[(size_t)s0 * F + col];
        f16x4 v1 = *(const f16x4*)&Hs[(size_t)s1 * F + col];
        f16x4 v2 = *(const f16x4*)&Hs[(size_t)s2 * F + col];
        f16x4 v3 = *(const f16x4*)&Hs[(size_t)s3 * F + col];
        a0 += ((float)v0[0] + (float)v1[0]) + ((float)v2[0] + (float)v3[0]);
        a1 += ((float)v0[1] + (float)v1[1]) + ((float)v2[1] + (float)v3[1]);
        a2 += ((float)v0[2] + (float)v1[2]) + ((float)v2[2] + (float)v3[2]);
        a3 += ((float)v0[3] + (float)v1[3]) + ((float)v2[3] + (float)v3[3]);
    }
    for (; e < end; ++e) {
        int s = csr[e];
        f16x4 v = *(const f16x4*)&Hs[(size_t)s * F + col];
        a0 += (float)v[0]; a1 += (float)v[1]; a2 += (float)v[2]; a3 += (float)v[3];
    }

    float dv = dinv[gid];
    float4 bb = *(const float4*)&bias[col];
    float4 o;
    o.x = dv * a0 + bb.x;
    o.y = dv * a1 + bb.y;
    o.z = dv * a2 + bb.z;
    o.w = dv * a3 + bb.w;
    if (RELU) {
        o.x = fmaxf(o.x, 0.f); o.y = fmaxf(o.y, 0.f);
        o.z = fmaxf(o.z, 0.f); o.w = fmaxf(o.w, 0.f);
    }
    *(float4*)&out[(size_t)gid * F + col] = o;
}

// ---------------- launch ----------------
extern "C" void kernel_launch(void* const* d_in, const int* in_sizes, int n_in,
                              void* d_out, int out_size, void* d_ws, size_t ws_size,
                              hipStream_t stream) {
    const float* x  = (const float*)d_in[0];
    const int*   ei = (const int*)d_in[1];
    const float* W1 = (const float*)d_in[2];
    const float* b1 = (const float*)d_in[3];
    const float* W2 = (const float*)d_in[4];
    const float* b2 = (const float*)d_in[5];
    float* out = (float*)d_out;

    const int N = in_sizes[0] / FIN;     // 50000
    const int E = in_sizes[1] / 2;       // 800000
    const int* src = ei;
    const int* dst = ei + E;

    char* w = (char*)d_ws;
    auto alloc = [&](size_t bytes) {
        void* p = (void*)w;
        w += (bytes + 255) & ~(size_t)255;
        return p;
    };
    int*      deg      = (int*)alloc((size_t)N * 4);
    float*    dinv     = (float*)alloc((size_t)N * 4);
    int*      rowptr   = (int*)alloc((size_t)(N + 1) * 4);
    int*      csr      = (int*)alloc((size_t)E * 4);
    int*      bsum     = (int*)alloc((size_t)256 * 4);
    int*      bhist    = (int*)alloc((size_t)MAXBUCK * 4);
    int*      bbase    = (int*)alloc((size_t)(MAXBUCK + 1) * 4);
    int*      bcur_pad = (int*)alloc((size_t)MAXBUCK * 16 * 4);
    uint2*    ebuf     = (uint2*)alloc((size_t)E * 8);
    _Float16* WT1      = (_Float16*)alloc((size_t)FIN * F1 * 2);
    _Float16* WT2      = (_Float16*)alloc((size_t)F1 * F2 * 2);
    _Float16* Hs1      = (_Float16*)alloc((size_t)N * F1 * 2);  // reused as Hs2
    float*    X2       = (float*)alloc((size_t)N * F1 * 4);

    const int nb     = (N + 1023) / 1024;
    const int nbuck  = (N + BUCKET_W - 1) >> BUCKET_SHIFT;   // 391
    const int nchunk = (E + CHUNK - 1) / CHUNK;

    // ---- CSR build (bucketized) ----
    hipMemsetAsync(bhist, 0, (size_t)MAXBUCK * 4, stream);
    bucket_hist<<<nchunk, 256, 0, stream>>>(dst, bhist, E);
    scan_bucket<<<1, 512, 0, stream>>>(bhist, bbase, bcur_pad, nbuck, E);
    bucket_fill<<<nchunk, 256, 0, stream>>>(src, dst, bcur_pad, ebuf, E);
    deg_bucket<<<nbuck, 256, 0, stream>>>(ebuf, bbase, deg, N);
    block_sum<<<nb, 256, 0, stream>>>(deg, bsum, N);
    scan_bsums<<<1, 64, 0, stream>>>(bsum, nb);
    scan_final<<<nb, 256, 0, stream>>>(deg, bsum, rowptr, dinv, N, E);
    csr_fill_bucket<<<nbuck, 256, 0, stream>>>(ebuf, bbase, rowptr, csr, N);

    // ---- weights ----
    cvt_wt<<<(FIN * F1 + 255) / 256, 256, 0, stream>>>(W1, WT1, FIN, F1);
    cvt_wt<<<(F1 * F2 + 255) / 256, 256, 0, stream>>>(W2, WT2, F1, F2);

    // layer 1: Hs1 = f16(dinv * (x @ W1)); X2 = relu(dinv*(Hs1[v]+sum)+b1)
    gemm_mfma<F1, FIN><<<(N + 63) / 64, 256, 0, stream>>>(x, WT1, dinv, Hs1, N);
    {
        int lpg = F1 / 4;
        int blocks = (int)(((size_t)N * lpg + 255) / 256);
        aggregate<F1, true><<<blocks, 256, 0, stream>>>(Hs1, rowptr, csr, dinv, b1, X2, N);
    }

    // layer 2: Hs2 = f16(dinv * (X2 @ W2)); out = dinv*(Hs2[v]+sum)+b2
    gemm_mfma<F2, F1><<<(N + 63) / 64, 256, 0, stream>>>(X2, WT2, dinv, Hs1, N);
    {
        int lpg = F2 / 4;
        int blocks = (int)(((size_t)N * lpg + 255) / 256);
        aggregate<F2, false><<<blocks, 256, 0, stream>>>(Hs1, rowptr, csr, dinv, b2, out, N);
    }
}

// Round 8
// 147.405 us; speedup vs baseline: 1.2001x; 1.2001x over previous
//
#include <hip/hip_runtime.h>

// ---------------- problem constants ----------------
#define FIN   256
#define F1    128
#define F2    64

typedef _Float16 f16x8 __attribute__((ext_vector_type(8)));
typedef _Float16 f16x4 __attribute__((ext_vector_type(4)));
typedef float    f32x4 __attribute__((ext_vector_type(4)));

// Buckets: 128 dst nodes per bucket (dst>>7). For N=50000 -> 391 buckets (<512).
#define BUCKET_SHIFT 7
#define BUCKET_W     128
#define MAXBUCK      512
#define CHUNK        2048   // edges per block in bucket passes

// ---------------- bucket histogram ----------------
__global__ __launch_bounds__(256) void bucket_hist(const int* __restrict__ dst,
                                                   int* __restrict__ bhist, int E) {
    __shared__ int h[MAXBUCK];
    for (int i = threadIdx.x; i < MAXBUCK; i += 256) h[i] = 0;
    __syncthreads();
    int base = blockIdx.x * CHUNK;
#pragma unroll
    for (int i = 0; i < CHUNK / 256; ++i) {
        int e = base + i * 256 + threadIdx.x;
        if (e < E) atomicAdd(&h[dst[e] >> BUCKET_SHIFT], 1);
    }
    __syncthreads();
    for (int i = threadIdx.x; i < MAXBUCK; i += 256)
        if (h[i]) atomicAdd(&bhist[i], h[i]);
}

// ---------------- scan buckets (1 block, 512 threads) ----------------
__global__ __launch_bounds__(512) void scan_bucket(const int* __restrict__ bhist,
                                                   int* __restrict__ bbase,
                                                   int* __restrict__ bcur_pad,
                                                   int nbuck, int E) {
    __shared__ int buf[2][512];
    int t = threadIdx.x;
    int v = (t < nbuck) ? bhist[t] : 0;
    buf[0][t] = v;
    __syncthreads();
    int cur = 0;
    for (int off = 1; off < 512; off <<= 1) {
        int x = buf[cur][t];
        if (t >= off) x += buf[cur][t - off];
        buf[cur ^ 1][t] = x;
        cur ^= 1;
        __syncthreads();
    }
    int excl = (t == 0) ? 0 : buf[cur][t - 1];
    if (t < nbuck) {
        bbase[t] = excl;
        bcur_pad[t * 16] = excl;      // 64B-padded cursor (atomic target)
    }
    if (t == 0) bbase[nbuck] = E;
}

// ---------------- partition edges into bucket-segmented ebuf ----------------
__global__ __launch_bounds__(256) void bucket_fill(const int* __restrict__ src,
                                                   const int* __restrict__ dst,
                                                   int* __restrict__ bcur_pad,
                                                   uint2* __restrict__ ebuf, int E) {
    __shared__ int h[MAXBUCK];
    __shared__ int base[MAXBUCK];
    for (int i = threadIdx.x; i < MAXBUCK; i += 256) h[i] = 0;
    __syncthreads();
    int cbase = blockIdx.x * CHUNK;
#pragma unroll
    for (int i = 0; i < CHUNK / 256; ++i) {
        int e = cbase + i * 256 + threadIdx.x;
        if (e < E) atomicAdd(&h[dst[e] >> BUCKET_SHIFT], 1);
    }
    __syncthreads();
    for (int i = threadIdx.x; i < MAXBUCK; i += 256) {
        int c = h[i];
        base[i] = c ? atomicAdd(&bcur_pad[i * 16], c) : 0;
        h[i] = 0;
    }
    __syncthreads();
#pragma unroll
    for (int i = 0; i < CHUNK / 256; ++i) {
        int e = cbase + i * 256 + threadIdx.x;
        if (e < E) {
            int d = dst[e], b = d >> BUCKET_SHIFT;
            int r = atomicAdd(&h[b], 1);
            ebuf[base[b] + r] = make_uint2((unsigned)src[e], (unsigned)d);
        }
    }
}

// ---------------- per-bucket degree count (LDS only) ----------------
__global__ __launch_bounds__(256) void deg_bucket(const uint2* __restrict__ ebuf,
                                                  const int* __restrict__ bbase,
                                                  int* __restrict__ deg, int n) {
    __shared__ int cnt[BUCKET_W];
    int k = blockIdx.x;
    if (threadIdx.x < BUCKET_W) cnt[threadIdx.x] = 0;
    __syncthreads();
    int beg = bbase[k], end = bbase[k + 1];
    for (int e = beg + threadIdx.x; e < end; e += 256)
        atomicAdd(&cnt[ebuf[e].y & (BUCKET_W - 1)], 1);
    __syncthreads();
    if (threadIdx.x < BUCKET_W) {
        int node = (k << BUCKET_SHIFT) + threadIdx.x;
        if (node < n) deg[node] = cnt[threadIdx.x];
    }
}

// ---------------- hierarchical scan over deg -> rowptr, dinv ----------------
__global__ __launch_bounds__(256) void block_sum(const int* __restrict__ deg,
                                                 int* __restrict__ bsum, int n) {
    int t = threadIdx.x;
    int base = blockIdx.x * 1024 + t * 4;
    int s = 0;
    if (base + 3 < n) {
        int4 v = *(const int4*)&deg[base];
        s = v.x + v.y + v.z + v.w;
    } else {
        for (int i = 0; i < 4; ++i)
            if (base + i < n) s += deg[base + i];
    }
#pragma unroll
    for (int off = 32; off > 0; off >>= 1) s += __shfl_down(s, off, 64);
    __shared__ int ws[4];
    if ((t & 63) == 0) ws[t >> 6] = s;
    __syncthreads();
    if (t == 0) bsum[blockIdx.x] = ws[0] + ws[1] + ws[2] + ws[3];
}

__global__ void scan_bsums(int* __restrict__ bsum, int nb) {
    if (threadIdx.x == 0) {
        int run = 0;
        for (int i = 0; i < nb; ++i) {
            int v = bsum[i];
            bsum[i] = run;
            run += v;
        }
    }
}

__global__ __launch_bounds__(256) void scan_final(const int* __restrict__ deg,
                                                  const int* __restrict__ bsum,
                                                  int* __restrict__ rowptr,
                                                  float* __restrict__ dinv,
                                                  int n, int E) {
    __shared__ int buf[2][256];
    int t = threadIdx.x;
    int base = blockIdx.x * 1024 + t * 4;
    int d[4] = {0, 0, 0, 0};
    if (base + 3 < n) {
        int4 v = *(const int4*)&deg[base];
        d[0] = v.x; d[1] = v.y; d[2] = v.z; d[3] = v.w;
    } else {
        for (int i = 0; i < 4; ++i)
            if (base + i < n) d[i] = deg[base + i];
    }
    int tsum = d[0] + d[1] + d[2] + d[3];
    buf[0][t] = tsum;
    __syncthreads();
    int cur = 0;
    for (int off = 1; off < 256; off <<= 1) {
        int v = buf[cur][t];
        if (t >= off) v += buf[cur][t - off];
        buf[cur ^ 1][t] = v;
        cur ^= 1;
        __syncthreads();
    }
    int run = bsum[blockIdx.x] + ((t == 0) ? 0 : buf[cur][t - 1]);
#pragma unroll
    for (int i = 0; i < 4; ++i) {
        int idx = base + i;
        if (idx < n) {
            rowptr[idx] = run;
            dinv[idx]   = rsqrtf((float)(d[i] + 1));  // +1 self loop
            run += d[i];
        }
    }
    if (blockIdx.x == 0 && t == 0) rowptr[n] = E;
}

// ---------------- per-bucket CSR fill (one block owns one csr window) -------
__global__ __launch_bounds__(256) void csr_fill_bucket(const uint2* __restrict__ ebuf,
                                                       const int* __restrict__ bbase,
                                                       const int* __restrict__ rowptr,
                                                       int* __restrict__ csr, int n) {
    __shared__ int lcur[BUCKET_W];
    int k = blockIdx.x;
    if (threadIdx.x < BUCKET_W) {
        int node = (k << BUCKET_SHIFT) + threadIdx.x;
        lcur[threadIdx.x] = (node < n) ? rowptr[node] : 0;
    }
    __syncthreads();
    int beg = bbase[k], end = bbase[k + 1];
    for (int e = beg + threadIdx.x; e < end; e += 256) {
        uint2 ed = ebuf[e];
        int pos = atomicAdd(&lcur[ed.y & (BUCKET_W - 1)], 1);
        csr[pos] = (int)ed.x;
    }
}

// ---------------- W -> W^T f16 conversion ----------------
__global__ void cvt_wt(const float* __restrict__ W, _Float16* __restrict__ WT,
                       int K, int Nn) {
    int idx = blockIdx.x * blockDim.x + threadIdx.x;
    if (idx < K * Nn) {
        int k = idx / Nn, n = idx % Nn;
        WT[(size_t)n * K + k] = (_Float16)W[idx];
    }
}

// ---------------- f16 MFMA GEMM: A in registers, B in LDS (staged once) ----
// Ch[M][BN]_f16 = dinv[row] * (A[M][K]_f32 @ W[K][BN]); WT is W^T f16 [BN][K].
// Each lane loads its OWN 256B of A upfront (16 float4, no LDS, no barriers);
// WT staged to padded LDS once. k-loop = ds_read + MFMA only.
template <int BN, int K>
__global__ __launch_bounds__(256) void gemm_mfma(const float* __restrict__ A,
                                                 const _Float16* __restrict__ WT,
                                                 const float* __restrict__ dinv,
                                                 _Float16* __restrict__ Ch, int M) {
    constexpr int NB = BN / 16;          // 8 or 4
    constexpr int CH = K / 32;           // k-chunks: 8 or 4
    constexpr int KP = K + 8;            // padded LDS row (f16): 528B/272B stride
    __shared__ _Float16 Bs[BN][KP];

    int tid  = threadIdx.x;
    int wave = tid >> 6, lane = tid & 63;
    int col  = lane & 15, kg = lane >> 4;
    int row0 = blockIdx.x * 64;
    int arow = row0 + wave * 16 + col;
    bool rowok = arow < M;

    // 1) issue ALL of this lane's A loads upfront (oldest in vmcnt queue)
    float4 pa[2 * CH];
    const float* Ab = A + (size_t)arow * K + kg * 8;
#pragma unroll
    for (int c = 0; c < CH; ++c) {
        pa[2 * c]     = make_float4(0.f, 0.f, 0.f, 0.f);
        pa[2 * c + 1] = make_float4(0.f, 0.f, 0.f, 0.f);
        if (rowok) {
            pa[2 * c]     = *(const float4*)(Ab + c * 32);
            pa[2 * c + 1] = *(const float4*)(Ab + c * 32 + 4);
        }
    }

    // 2) stage WT -> LDS (padded rows), once
    constexpr int TOT = BN * K / 8;      // f16x8 units
#pragma unroll
    for (int l = 0; l < TOT / 256; ++l) {
        int u  = l * 256 + tid;
        int r  = u / (K / 8);
        int c8 = u % (K / 8);
        *(f16x8*)&Bs[r][c8 * 8] = *(const f16x8*)&WT[(size_t)r * K + c8 * 8];
    }
    __syncthreads();

    f32x4 acc[NB];
#pragma unroll
    for (int j = 0; j < NB; ++j) acc[j] = (f32x4){0.f, 0.f, 0.f, 0.f};

    // 3) k-loop: registers + LDS only (no global waits, no barriers)
#pragma unroll
    for (int c = 0; c < CH; ++c) {
        float4 lo = pa[2 * c], hi = pa[2 * c + 1];
        f16x8 a;
        a[0] = (_Float16)lo.x; a[1] = (_Float16)lo.y;
        a[2] = (_Float16)lo.z; a[3] = (_Float16)lo.w;
        a[4] = (_Float16)hi.x; a[5] = (_Float16)hi.y;
        a[6] = (_Float16)hi.z; a[7] = (_Float16)hi.w;
#pragma unroll
        for (int j = 0; j < NB; ++j) {
            f16x8 b = *(const f16x8*)&Bs[j * 16 + col][c * 32 + kg * 8];
            acc[j] = __builtin_amdgcn_mfma_f32_16x16x32_f16(a, b, acc[j], 0, 0, 0);
        }
    }

    // epilogue: D row = wave*16 + kg*4 + r, col = j*16 + col
    int rbase = row0 + wave * 16 + kg * 4;
#pragma unroll
    for (int r = 0; r < 4; ++r) {
        int m = rbase + r;
        if (m < M) {
            float dv = dinv[m];
#pragma unroll
            for (int j = 0; j < NB; ++j)
                Ch[(size_t)m * BN + j * 16 + col] = (_Float16)(dv * acc[j][r]);
        }
    }
}

// ---------------- gather aggregation: f16 rows, f32 accumulate ----------------
template <int F, bool RELU>
__global__ __launch_bounds__(256) void aggregate(const _Float16* __restrict__ Hs,
                                                 const int* __restrict__ rowptr,
                                                 const int* __restrict__ csr,
                                                 const float* __restrict__ dinv,
                                                 const float* __restrict__ bias,
                                                 float* __restrict__ out, int n) {
    constexpr int LPG = F / 4;                  // 32 (F=128) or 16 (F=64)
    int gid = (blockIdx.x * blockDim.x + threadIdx.x) / LPG;
    int sub = threadIdx.x & (LPG - 1);
    if (gid >= n) return;
    const int col = sub * 4;

    f16x4 h = *(const f16x4*)&Hs[(size_t)gid * F + col];
    float a0 = (float)h[0], a1 = (float)h[1], a2 = (float)h[2], a3 = (float)h[3];

    int beg = rowptr[gid], end = rowptr[gid + 1];
    int e = beg;

    for (; e + 8 <= end; e += 8) {
        int s0 = csr[e + 0], s1 = csr[e + 1], s2 = csr[e + 2], s3 = csr[e + 3];
        int s4 = csr[e + 4], s5 = csr[e + 5], s6 = csr[e + 6], s7 = csr[e + 7];
        f16x4 v0 = *(const f16x4*)&Hs[(size_t)s0 * F + col];
        f16x4 v1 = *(const f16x4*)&Hs[(size_t)s1 * F + col];
        f16x4 v2 = *(const f16x4*)&Hs[(size_t)s2 * F + col];
        f16x4 v3 = *(const f16x4*)&Hs[(size_t)s3 * F + col];
        f16x4 v4 = *(const f16x4*)&Hs[(size_t)s4 * F + col];
        f16x4 v5 = *(const f16x4*)&Hs[(size_t)s5 * F + col];
        f16x4 v6 = *(const f16x4*)&Hs[(size_t)s6 * F + col];
        f16x4 v7 = *(const f16x4*)&Hs[(size_t)s7 * F + col];
        a0 += (((float)v0[0] + (float)v1[0]) + ((float)v2[0] + (float)v3[0]))
            + (((float)v4[0] + (float)v5[0]) + ((float)v6[0] + (float)v7[0]));
        a1 += (((float)v0[1] + (float)v1[1]) + ((float)v2[1] + (float)v3[1]))
            + (((float)v4[1] + (float)v5[1]) + ((float)v6[1] + (float)v7[1]));
        a2 += (((float)v0[2] + (float)v1[2]) + ((float)v2[2] + (float)v3[2]))
            + (((float)v4[2] + (float)v5[2]) + ((float)v6[2] + (float)v7[2]));
        a3 += (((float)v0[3] + (float)v1[3]) + ((float)v2[3] + (float)v3[3]))
            + (((float)v4[3] + (float)v5[3]) + ((float)v6[3] + (float)v7[3]));
    }
    for (; e + 4 <= end; e += 4) {
        int s0 = csr[e + 0], s1 = csr[e + 1], s2 = csr[e + 2], s3 = csr[e + 3];
        f16x4 v0 = *(const f16x4*)&Hs[(size_t)s0 * F + col];
        f16x4 v1 = *(const f16x4*)&Hs[(size_t)s1 * F + col];
        f16x4 v2 = *(const f16x4*)&Hs[(size_t)s2 * F + col];
        f16x4 v3 = *(const f16x4*)&Hs[(size_t)s3 * F + col];
        a0 += ((float)v0[0] + (float)v1[0]) + ((float)v2[0] + (float)v3[0]);
        a1 += ((float)v0[1] + (float)v1[1]) + ((float)v2[1] + (float)v3[1]);
        a2 += ((float)v0[2] + (float)v1[2]) + ((float)v2[2] + (float)v3[2]);
        a3 += ((float)v0[3] + (float)v1[3]) + ((float)v2[3] + (float)v3[3]);
    }
    for (; e < end; ++e) {
        int s = csr[e];
        f16x4 v = *(const f16x4*)&Hs[(size_t)s * F + col];
        a0 += (float)v[0]; a1 += (float)v[1]; a2 += (float)v[2]; a3 += (float)v[3];
    }

    float dv = dinv[gid];
    float4 bb = *(const float4*)&bias[col];
    float4 o;
    o.x = dv * a0 + bb.x;
    o.y = dv * a1 + bb.y;
    o.z = dv * a2 + bb.z;
    o.w = dv * a3 + bb.w;
    if (RELU) {
        o.x = fmaxf(o.x, 0.f); o.y = fmaxf(o.y, 0.f);
        o.z = fmaxf(o.z, 0.f); o.w = fmaxf(o.w, 0.f);
    }
    *(float4*)&out[(size_t)gid * F + col] = o;
}

// ---------------- launch ----------------
extern "C" void kernel_launch(void* const* d_in, const int* in_sizes, int n_in,
                              void* d_out, int out_size, void* d_ws, size_t ws_size,
                              hipStream_t stream) {
    const float* x  = (const float*)d_in[0];
    const int*   ei = (const int*)d_in[1];
    const float* W1 = (const float*)d_in[2];
    const float* b1 = (const float*)d_in[3];
    const float* W2 = (const float*)d_in[4];
    const float* b2 = (const float*)d_in[5];
    float* out = (float*)d_out;

    const int N = in_sizes[0] / FIN;     // 50000
    const int E = in_sizes[1] / 2;       // 800000
    const int* src = ei;
    const int* dst = ei + E;

    char* w = (char*)d_ws;
    auto alloc = [&](size_t bytes) {
        void* p = (void*)w;
        w += (bytes + 255) & ~(size_t)255;
        return p;
    };
    int*      deg      = (int*)alloc((size_t)N * 4);
    float*    dinv     = (float*)alloc((size_t)N * 4);
    int*      rowptr   = (int*)alloc((size_t)(N + 1) * 4);
    int*      csr      = (int*)alloc((size_t)E * 4);
    int*      bsum     = (int*)alloc((size_t)256 * 4);
    int*      bhist    = (int*)alloc((size_t)MAXBUCK * 4);
    int*      bbase    = (int*)alloc((size_t)(MAXBUCK + 1) * 4);
    int*      bcur_pad = (int*)alloc((size_t)MAXBUCK * 16 * 4);
    uint2*    ebuf     = (uint2*)alloc((size_t)E * 8);
    _Float16* WT1      = (_Float16*)alloc((size_t)FIN * F1 * 2);
    _Float16* WT2      = (_Float16*)alloc((size_t)F1 * F2 * 2);
    _Float16* Hs1      = (_Float16*)alloc((size_t)N * F1 * 2);  // reused as Hs2
    float*    X2       = (float*)alloc((size_t)N * F1 * 4);

    const int nb     = (N + 1023) / 1024;
    const int nbuck  = (N + BUCKET_W - 1) >> BUCKET_SHIFT;   // 391
    const int nchunk = (E + CHUNK - 1) / CHUNK;

    // ---- CSR build (bucketized) ----
    hipMemsetAsync(bhist, 0, (size_t)MAXBUCK * 4, stream);
    bucket_hist<<<nchunk, 256, 0, stream>>>(dst, bhist, E);
    scan_bucket<<<1, 512, 0, stream>>>(bhist, bbase, bcur_pad, nbuck, E);
    bucket_fill<<<nchunk, 256, 0, stream>>>(src, dst, bcur_pad, ebuf, E);
    deg_bucket<<<nbuck, 256, 0, stream>>>(ebuf, bbase, deg, N);
    block_sum<<<nb, 256, 0, stream>>>(deg, bsum, N);
    scan_bsums<<<1, 64, 0, stream>>>(bsum, nb);
    scan_final<<<nb, 256, 0, stream>>>(deg, bsum, rowptr, dinv, N, E);
    csr_fill_bucket<<<nbuck, 256, 0, stream>>>(ebuf, bbase, rowptr, csr, N);

    // ---- weights ----
    cvt_wt<<<(FIN * F1 + 255) / 256, 256, 0, stream>>>(W1, WT1, FIN, F1);
    cvt_wt<<<(F1 * F2 + 255) / 256, 256, 0, stream>>>(W2, WT2, F1, F2);

    // layer 1: Hs1 = f16(dinv * (x @ W1)); X2 = relu(dinv*(Hs1[v]+sum)+b1)
    gemm_mfma<F1, FIN><<<(N + 63) / 64, 256, 0, stream>>>(x, WT1, dinv, Hs1, N);
    {
        int lpg = F1 / 4;
        int blocks = (int)(((size_t)N * lpg + 255) / 256);
        aggregate<F1, true><<<blocks, 256, 0, stream>>>(Hs1, rowptr, csr, dinv, b1, X2, N);
    }

    // layer 2: Hs2 = f16(dinv * (X2 @ W2)); out = dinv*(Hs2[v]+sum)+b2
    gemm_mfma<F2, F1><<<(N + 63) / 64, 256, 0, stream>>>(X2, WT2, dinv, Hs1, N);
    {
        int lpg = F2 / 4;
        int blocks = (int)(((size_t)N * lpg + 255) / 256);
        aggregate<F2, false><<<blocks, 256, 0, stream>>>(Hs1, rowptr, csr, dinv, b2, out, N);
    }
}

// Round 9
// 146.252 us; speedup vs baseline: 1.2095x; 1.0079x over previous
//
#include <hip/hip_runtime.h>

// ---------------- problem constants ----------------
#define FIN   256
#define F1    128
#define F2    64

typedef _Float16 f16x8 __attribute__((ext_vector_type(8)));
typedef _Float16 f16x4 __attribute__((ext_vector_type(4)));
typedef float    f32x4 __attribute__((ext_vector_type(4)));

// Buckets: 128 dst nodes per bucket (dst>>7). For N=50000 -> 391 buckets (<512).
// Packed edge: (src << 7) | (dst & 127)  -- src < 2^25 required (N=50000 ok).
#define BUCKET_SHIFT 7
#define BUCKET_W     128
#define MAXBUCK      512
#define CHUNK        2048   // edges per block in bucket passes

// ---------------- zero the bucket histogram (replaces hipMemsetAsync) -------
__global__ void zero_hist(int* __restrict__ bhist) {
    bhist[threadIdx.x] = 0;
}

// ---------------- bucket histogram ----------------
__global__ __launch_bounds__(256) void bucket_hist(const int* __restrict__ dst,
                                                   int* __restrict__ bhist, int E) {
    __shared__ int h[MAXBUCK];
    for (int i = threadIdx.x; i < MAXBUCK; i += 256) h[i] = 0;
    __syncthreads();
    int base = blockIdx.x * CHUNK;
#pragma unroll
    for (int i = 0; i < CHUNK / 256; ++i) {
        int e = base + i * 256 + threadIdx.x;
        if (e < E) atomicAdd(&h[dst[e] >> BUCKET_SHIFT], 1);
    }
    __syncthreads();
    for (int i = threadIdx.x; i < MAXBUCK; i += 256)
        if (h[i]) atomicAdd(&bhist[i], h[i]);
}

// ---------------- scan buckets (1 block, 512 threads) ----------------
__global__ __launch_bounds__(512) void scan_bucket(const int* __restrict__ bhist,
                                                   int* __restrict__ bbase,
                                                   int* __restrict__ bcur_pad,
                                                   int nbuck, int E) {
    __shared__ int buf[2][512];
    int t = threadIdx.x;
    int v = (t < nbuck) ? bhist[t] : 0;
    buf[0][t] = v;
    __syncthreads();
    int cur = 0;
    for (int off = 1; off < 512; off <<= 1) {
        int x = buf[cur][t];
        if (t >= off) x += buf[cur][t - off];
        buf[cur ^ 1][t] = x;
        cur ^= 1;
        __syncthreads();
    }
    int excl = (t == 0) ? 0 : buf[cur][t - 1];
    if (t < nbuck) {
        bbase[t] = excl;
        bcur_pad[t * 16] = excl;      // 64B-padded cursor (atomic target)
    }
    if (t == 0) bbase[nbuck] = E;
}

// ---------------- partition edges into bucket-segmented packed ebuf ---------
__global__ __launch_bounds__(256) void bucket_fill(const int* __restrict__ src,
                                                   const int* __restrict__ dst,
                                                   int* __restrict__ bcur_pad,
                                                   unsigned* __restrict__ ebuf, int E) {
    __shared__ int h[MAXBUCK];
    __shared__ int base[MAXBUCK];
    for (int i = threadIdx.x; i < MAXBUCK; i += 256) h[i] = 0;
    __syncthreads();
    int cbase = blockIdx.x * CHUNK;
#pragma unroll
    for (int i = 0; i < CHUNK / 256; ++i) {
        int e = cbase + i * 256 + threadIdx.x;
        if (e < E) atomicAdd(&h[dst[e] >> BUCKET_SHIFT], 1);
    }
    __syncthreads();
    for (int i = threadIdx.x; i < MAXBUCK; i += 256) {
        int c = h[i];
        base[i] = c ? atomicAdd(&bcur_pad[i * 16], c) : 0;
        h[i] = 0;
    }
    __syncthreads();
#pragma unroll
    for (int i = 0; i < CHUNK / 256; ++i) {
        int e = cbase + i * 256 + threadIdx.x;
        if (e < E) {
            int d = dst[e], b = d >> BUCKET_SHIFT;
            int r = atomicAdd(&h[b], 1);
            ebuf[base[b] + r] = ((unsigned)src[e] << BUCKET_SHIFT) | (unsigned)(d & (BUCKET_W - 1));
        }
    }
}

// ---------------- per-bucket degree count (LDS only) ----------------
__global__ __launch_bounds__(256) void deg_bucket(const unsigned* __restrict__ ebuf,
                                                  const int* __restrict__ bbase,
                                                  int* __restrict__ deg, int n) {
    __shared__ int cnt[BUCKET_W];
    int k = blockIdx.x;
    if (threadIdx.x < BUCKET_W) cnt[threadIdx.x] = 0;
    __syncthreads();
    int beg = bbase[k], end = bbase[k + 1];
    for (int e = beg + threadIdx.x; e < end; e += 256)
        atomicAdd(&cnt[ebuf[e] & (BUCKET_W - 1)], 1);
    __syncthreads();
    if (threadIdx.x < BUCKET_W) {
        int node = (k << BUCKET_SHIFT) + threadIdx.x;
        if (node < n) deg[node] = cnt[threadIdx.x];
    }
}

// ---------------- hierarchical scan over deg -> rowptr, dinv ----------------
__global__ __launch_bounds__(256) void block_sum(const int* __restrict__ deg,
                                                 int* __restrict__ bsum, int n) {
    int t = threadIdx.x;
    int base = blockIdx.x * 1024 + t * 4;
    int s = 0;
    if (base + 3 < n) {
        int4 v = *(const int4*)&deg[base];
        s = v.x + v.y + v.z + v.w;
    } else {
        for (int i = 0; i < 4; ++i)
            if (base + i < n) s += deg[base + i];
    }
#pragma unroll
    for (int off = 32; off > 0; off >>= 1) s += __shfl_down(s, off, 64);
    __shared__ int ws[4];
    if ((t & 63) == 0) ws[t >> 6] = s;
    __syncthreads();
    if (t == 0) bsum[blockIdx.x] = ws[0] + ws[1] + ws[2] + ws[3];
}

__global__ void scan_bsums(int* __restrict__ bsum, int nb) {
    if (threadIdx.x == 0) {
        int run = 0;
        for (int i = 0; i < nb; ++i) {
            int v = bsum[i];
            bsum[i] = run;
            run += v;
        }
    }
}

__global__ __launch_bounds__(256) void scan_final(const int* __restrict__ deg,
                                                  const int* __restrict__ bsum,
                                                  int* __restrict__ rowptr,
                                                  float* __restrict__ dinv,
                                                  int n, int E) {
    __shared__ int buf[2][256];
    int t = threadIdx.x;
    int base = blockIdx.x * 1024 + t * 4;
    int d[4] = {0, 0, 0, 0};
    if (base + 3 < n) {
        int4 v = *(const int4*)&deg[base];
        d[0] = v.x; d[1] = v.y; d[2] = v.z; d[3] = v.w;
    } else {
        for (int i = 0; i < 4; ++i)
            if (base + i < n) d[i] = deg[base + i];
    }
    int tsum = d[0] + d[1] + d[2] + d[3];
    buf[0][t] = tsum;
    __syncthreads();
    int cur = 0;
    for (int off = 1; off < 256; off <<= 1) {
        int v = buf[cur][t];
        if (t >= off) v += buf[cur][t - off];
        buf[cur ^ 1][t] = v;
        cur ^= 1;
        __syncthreads();
    }
    int run = bsum[blockIdx.x] + ((t == 0) ? 0 : buf[cur][t - 1]);
#pragma unroll
    for (int i = 0; i < 4; ++i) {
        int idx = base + i;
        if (idx < n) {
            rowptr[idx] = run;
            dinv[idx]   = rsqrtf((float)(d[i] + 1));  // +1 self loop
            run += d[i];
        }
    }
    if (blockIdx.x == 0 && t == 0) rowptr[n] = E;
}

// ---------------- per-bucket CSR fill (one block owns one csr window) -------
__global__ __launch_bounds__(256) void csr_fill_bucket(const unsigned* __restrict__ ebuf,
                                                       const int* __restrict__ bbase,
                                                       const int* __restrict__ rowptr,
                                                       int* __restrict__ csr, int n) {
    __shared__ int lcur[BUCKET_W];
    int k = blockIdx.x;
    if (threadIdx.x < BUCKET_W) {
        int node = (k << BUCKET_SHIFT) + threadIdx.x;
        lcur[threadIdx.x] = (node < n) ? rowptr[node] : 0;
    }
    __syncthreads();
    int beg = bbase[k], end = bbase[k + 1];
    for (int e = beg + threadIdx.x; e < end; e += 256) {
        unsigned ed = ebuf[e];
        int pos = atomicAdd(&lcur[ed & (BUCKET_W - 1)], 1);
        csr[pos] = (int)(ed >> BUCKET_SHIFT);
    }
}

// ---------------- W -> W^T f16 conversion ----------------
__global__ void cvt_wt(const float* __restrict__ W, _Float16* __restrict__ WT,
                       int K, int Nn) {
    int idx = blockIdx.x * blockDim.x + threadIdx.x;
    if (idx < K * Nn) {
        int k = idx / Nn, n = idx % Nn;
        WT[(size_t)n * K + k] = (_Float16)W[idx];
    }
}

// ---------------- f16 MFMA GEMM: A in registers, B in LDS (staged once) ----
template <int BN, int K>
__global__ __launch_bounds__(256) void gemm_mfma(const float* __restrict__ A,
                                                 const _Float16* __restrict__ WT,
                                                 const float* __restrict__ dinv,
                                                 _Float16* __restrict__ Ch, int M) {
    constexpr int NB = BN / 16;          // 8 or 4
    constexpr int CH = K / 32;           // k-chunks: 8 or 4
    constexpr int KP = K + 8;            // padded LDS row (f16)
    __shared__ _Float16 Bs[BN][KP];

    int tid  = threadIdx.x;
    int wave = tid >> 6, lane = tid & 63;
    int col  = lane & 15, kg = lane >> 4;
    int row0 = blockIdx.x * 64;
    int arow = row0 + wave * 16 + col;
    bool rowok = arow < M;

    // 1) issue ALL of this lane's A loads upfront
    float4 pa[2 * CH];
    const float* Ab = A + (size_t)arow * K + kg * 8;
#pragma unroll
    for (int c = 0; c < CH; ++c) {
        pa[2 * c]     = make_float4(0.f, 0.f, 0.f, 0.f);
        pa[2 * c + 1] = make_float4(0.f, 0.f, 0.f, 0.f);
        if (rowok) {
            pa[2 * c]     = *(const float4*)(Ab + c * 32);
            pa[2 * c + 1] = *(const float4*)(Ab + c * 32 + 4);
        }
    }

    // 2) stage WT -> LDS (padded rows), once
    constexpr int TOT = BN * K / 8;      // f16x8 units
#pragma unroll
    for (int l = 0; l < TOT / 256; ++l) {
        int u  = l * 256 + tid;
        int r  = u / (K / 8);
        int c8 = u % (K / 8);
        *(f16x8*)&Bs[r][c8 * 8] = *(const f16x8*)&WT[(size_t)r * K + c8 * 8];
    }
    __syncthreads();

    f32x4 acc[NB];
#pragma unroll
    for (int j = 0; j < NB; ++j) acc[j] = (f32x4){0.f, 0.f, 0.f, 0.f};

    // 3) k-loop: registers + LDS only
#pragma unroll
    for (int c = 0; c < CH; ++c) {
        float4 lo = pa[2 * c], hi = pa[2 * c + 1];
        f16x8 a;
        a[0] = (_Float16)lo.x; a[1] = (_Float16)lo.y;
        a[2] = (_Float16)lo.z; a[3] = (_Float16)lo.w;
        a[4] = (_Float16)hi.x; a[5] = (_Float16)hi.y;
        a[6] = (_Float16)hi.z; a[7] = (_Float16)hi.w;
#pragma unroll
        for (int j = 0; j < NB; ++j) {
            f16x8 b = *(const f16x8*)&Bs[j * 16 + col][c * 32 + kg * 8];
            acc[j] = __builtin_amdgcn_mfma_f32_16x16x32_f16(a, b, acc[j], 0, 0, 0);
        }
    }

    // epilogue
    int rbase = row0 + wave * 16 + kg * 4;
#pragma unroll
    for (int r = 0; r < 4; ++r) {
        int m = rbase + r;
        if (m < M) {
            float dv = dinv[m];
#pragma unroll
            for (int j = 0; j < NB; ++j)
                Ch[(size_t)m * BN + j * 16 + col] = (_Float16)(dv * acc[j][r]);
        }
    }
}

// ---------------- gather aggregation: f16 rows, f32 accumulate ----------------
template <int F, bool RELU>
__global__ __launch_bounds__(256) void aggregate(const _Float16* __restrict__ Hs,
                                                 const int* __restrict__ rowptr,
                                                 const int* __restrict__ csr,
                                                 const float* __restrict__ dinv,
                                                 const float* __restrict__ bias,
                                                 float* __restrict__ out, int n) {
    constexpr int LPG = F / 4;                  // 32 (F=128) or 16 (F=64)
    int gid = (blockIdx.x * blockDim.x + threadIdx.x) / LPG;
    int sub = threadIdx.x & (LPG - 1);
    if (gid >= n) return;
    const int col = sub * 4;

    f16x4 h = *(const f16x4*)&Hs[(size_t)gid * F + col];
    float a0 = (float)h[0], a1 = (float)h[1], a2 = (float)h[2], a3 = (float)h[3];

    int beg = rowptr[gid], end = rowptr[gid + 1];
    int e = beg;

    for (; e + 8 <= end; e += 8) {
        int s0 = csr[e + 0], s1 = csr[e + 1], s2 = csr[e + 2], s3 = csr[e + 3];
        int s4 = csr[e + 4], s5 = csr[e + 5], s6 = csr[e + 6], s7 = csr[e + 7];
        f16x4 v0 = *(const f16x4*)&Hs[(size_t)s0 * F + col];
        f16x4 v1 = *(const f16x4*)&Hs[(size_t)s1 * F + col];
        f16x4 v2 = *(const f16x4*)&Hs[(size_t)s2 * F + col];
        f16x4 v3 = *(const f16x4*)&Hs[(size_t)s3 * F + col];
        f16x4 v4 = *(const f16x4*)&Hs[(size_t)s4 * F + col];
        f16x4 v5 = *(const f16x4*)&Hs[(size_t)s5 * F + col];
        f16x4 v6 = *(const f16x4*)&Hs[(size_t)s6 * F + col];
        f16x4 v7 = *(const f16x4*)&Hs[(size_t)s7 * F + col];
        a0 += (((float)v0[0] + (float)v1[0]) + ((float)v2[0] + (float)v3[0]))
            + (((float)v4[0] + (float)v5[0]) + ((float)v6[0] + (float)v7[0]));
        a1 += (((float)v0[1] + (float)v1[1]) + ((float)v2[1] + (float)v3[1]))
            + (((float)v4[1] + (float)v5[1]) + ((float)v6[1] + (float)v7[1]));
        a2 += (((float)v0[2] + (float)v1[2]) + ((float)v2[2] + (float)v3[2]))
            + (((float)v4[2] + (float)v5[2]) + ((float)v6[2] + (float)v7[2]));
        a3 += (((float)v0[3] + (float)v1[3]) + ((float)v2[3] + (float)v3[3]))
            + (((float)v4[3] + (float)v5[3]) + ((float)v6[3] + (float)v7[3]));
    }
    for (; e + 4 <= end; e += 4) {
        int s0 = csr[e + 0], s1 = csr[e + 1], s2 = csr[e + 2], s3 = csr[e + 3];
        f16x4 v0 = *(const f16x4*)&Hs[(size_t)s0 * F + col];
        f16x4 v1 = *(const f16x4*)&Hs[(size_t)s1 * F + col];
        f16x4 v2 = *(const f16x4*)&Hs[(size_t)s2 * F + col];
        f16x4 v3 = *(const f16x4*)&Hs[(size_t)s3 * F + col];
        a0 += ((float)v0[0] + (float)v1[0]) + ((float)v2[0] + (float)v3[0]);
        a1 += ((float)v0[1] + (float)v1[1]) + ((float)v2[1] + (float)v3[1]);
        a2 += ((float)v0[2] + (float)v1[2]) + ((float)v2[2] + (float)v3[2]);
        a3 += ((float)v0[3] + (float)v1[3]) + ((float)v2[3] + (float)v3[3]);
    }
    for (; e < end; ++e) {
        int s = csr[e];
        f16x4 v = *(const f16x4*)&Hs[(size_t)s * F + col];
        a0 += (float)v[0]; a1 += (float)v[1]; a2 += (float)v[2]; a3 += (float)v[3];
    }

    float dv = dinv[gid];
    float4 bb = *(const float4*)&bias[col];
    float4 o;
    o.x = dv * a0 + bb.x;
    o.y = dv * a1 + bb.y;
    o.z = dv * a2 + bb.z;
    o.w = dv * a3 + bb.w;
    if (RELU) {
        o.x = fmaxf(o.x, 0.f); o.y = fmaxf(o.y, 0.f);
        o.z = fmaxf(o.z, 0.f); o.w = fmaxf(o.w, 0.f);
    }
    *(float4*)&out[(size_t)gid * F + col] = o;
}

// ---------------- launch ----------------
extern "C" void kernel_launch(void* const* d_in, const int* in_sizes, int n_in,
                              void* d_out, int out_size, void* d_ws, size_t ws_size,
                              hipStream_t stream) {
    const float* x  = (const float*)d_in[0];
    const int*   ei = (const int*)d_in[1];
    const float* W1 = (const float*)d_in[2];
    const float* b1 = (const float*)d_in[3];
    const float* W2 = (const float*)d_in[4];
    const float* b2 = (const float*)d_in[5];
    float* out = (float*)d_out;

    const int N = in_sizes[0] / FIN;     // 50000
    const int E = in_sizes[1] / 2;       // 800000
    const int* src = ei;
    const int* dst = ei + E;

    char* w = (char*)d_ws;
    auto alloc = [&](size_t bytes) {
        void* p = (void*)w;
        w += (bytes + 255) & ~(size_t)255;
        return p;
    };
    int*      deg      = (int*)alloc((size_t)N * 4);
    float*    dinv     = (float*)alloc((size_t)N * 4);
    int*      rowptr   = (int*)alloc((size_t)(N + 1) * 4);
    int*      csr      = (int*)alloc((size_t)E * 4);
    int*      bsum     = (int*)alloc((size_t)256 * 4);
    int*      bhist    = (int*)alloc((size_t)MAXBUCK * 4);
    int*      bbase    = (int*)alloc((size_t)(MAXBUCK + 1) * 4);
    int*      bcur_pad = (int*)alloc((size_t)MAXBUCK * 16 * 4);
    unsigned* ebuf     = (unsigned*)alloc((size_t)E * 4);
    _Float16* WT1      = (_Float16*)alloc((size_t)FIN * F1 * 2);
    _Float16* WT2      = (_Float16*)alloc((size_t)F1 * F2 * 2);
    _Float16* Hs1      = (_Float16*)alloc((size_t)N * F1 * 2);  // reused as Hs2
    float*    X2       = (float*)alloc((size_t)N * F1 * 4);

    const int nb     = (N + 1023) / 1024;
    const int nbuck  = (N + BUCKET_W - 1) >> BUCKET_SHIFT;   // 391
    const int nchunk = (E + CHUNK - 1) / CHUNK;

    // ---- CSR build (bucketized) ----
    zero_hist<<<1, MAXBUCK, 0, stream>>>(bhist);
    bucket_hist<<<nchunk, 256, 0, stream>>>(dst, bhist, E);
    scan_bucket<<<1, 512, 0, stream>>>(bhist, bbase, bcur_pad, nbuck, E);
    bucket_fill<<<nchunk, 256, 0, stream>>>(src, dst, bcur_pad, ebuf, E);
    deg_bucket<<<nbuck, 256, 0, stream>>>(ebuf, bbase, deg, N);
    block_sum<<<nb, 256, 0, stream>>>(deg, bsum, N);
    scan_bsums<<<1, 64, 0, stream>>>(bsum, nb);
    scan_final<<<nb, 256, 0, stream>>>(deg, bsum, rowptr, dinv, N, E);
    csr_fill_bucket<<<nbuck, 256, 0, stream>>>(ebuf, bbase, rowptr, csr, N);

    // ---- weights ----
    cvt_wt<<<(FIN * F1 + 255) / 256, 256, 0, stream>>>(W1, WT1, FIN, F1);
    cvt_wt<<<(F1 * F2 + 255) / 256, 256, 0, stream>>>(W2, WT2, F1, F2);

    // layer 1: Hs1 = f16(dinv * (x @ W1)); X2 = relu(dinv*(Hs1[v]+sum)+b1)
    gemm_mfma<F1, FIN><<<(N + 63) / 64, 256, 0, stream>>>(x, WT1, dinv, Hs1, N);
    {
        int lpg = F1 / 4;
        int blocks = (int)(((size_t)N * lpg + 255) / 256);
        aggregate<F1, true><<<blocks, 256, 0, stream>>>(Hs1, rowptr, csr, dinv, b1, X2, N);
    }

    // layer 2: Hs2 = f16(dinv * (X2 @ W2)); out = dinv*(Hs2[v]+sum)+b2
    gemm_mfma<F2, F1><<<(N + 63) / 64, 256, 0, stream>>>(X2, WT2, dinv, Hs1, N);
    {
        int lpg = F2 / 4;
        int blocks = (int)(((size_t)N * lpg + 255) / 256);
        aggregate<F2, false><<<blocks, 256, 0, stream>>>(Hs1, rowptr, csr, dinv, b2, out, N);
    }
}

// Round 10
// 133.256 us; speedup vs baseline: 1.3275x; 1.0975x over previous
//
#include <hip/hip_runtime.h>

// ---------------- problem constants ----------------
#define FIN   256
#define F1    128
#define F2    64

typedef _Float16 f16x8 __attribute__((ext_vector_type(8)));
typedef _Float16 f16x4 __attribute__((ext_vector_type(4)));
typedef float    f32x4 __attribute__((ext_vector_type(4)));

// Buckets: 128 dst nodes per bucket (dst>>7). For N=50000 -> 391 buckets (<512).
// Packed edge: (src << 7) | (dst & 127)  -- src < 2^25 required (N=50000 ok).
#define BUCKET_SHIFT 7
#define BUCKET_W     128
#define MAXBUCK      512
#define CHUNK        8192   // edges per block in bucket passes (long runs -> low write amp)

// ---------------- prep: zero bhist + convert W1,W2 -> WT f16 (one kernel) ----
__global__ __launch_bounds__(256) void prep(const float* __restrict__ W1,
                                            const float* __restrict__ W2,
                                            _Float16* __restrict__ WT1,
                                            _Float16* __restrict__ WT2,
                                            int* __restrict__ bhist) {
    int b = blockIdx.x;
    if (b == 0) {
        for (int i = threadIdx.x; i < MAXBUCK; i += 256) bhist[i] = 0;
        return;
    }
    int idx = (b - 1) * 256 + threadIdx.x;
    if (idx < FIN * F1) {
        int k = idx / F1, n = idx % F1;
        WT1[(size_t)n * FIN + k] = (_Float16)W1[idx];
    } else {
        int j = idx - FIN * F1;
        if (j < F1 * F2) {
            int k = j / F2, n = j % F2;
            WT2[(size_t)n * F1 + k] = (_Float16)W2[j];
        }
    }
}

// ---------------- bucket histogram ----------------
__global__ __launch_bounds__(256) void bucket_hist(const int* __restrict__ dst,
                                                   int* __restrict__ bhist, int E) {
    __shared__ int h[MAXBUCK];
    for (int i = threadIdx.x; i < MAXBUCK; i += 256) h[i] = 0;
    __syncthreads();
    int base = blockIdx.x * CHUNK;
    int lim  = min(base + CHUNK, E);
    for (int e = base + threadIdx.x; e < lim; e += 256)
        atomicAdd(&h[dst[e] >> BUCKET_SHIFT], 1);
    __syncthreads();
    for (int i = threadIdx.x; i < MAXBUCK; i += 256)
        if (h[i]) atomicAdd(&bhist[i], h[i]);
}

// ---------------- scan buckets (1 block, 512 threads) ----------------
__global__ __launch_bounds__(512) void scan_bucket(const int* __restrict__ bhist,
                                                   int* __restrict__ bbase,
                                                   int* __restrict__ bcur_pad,
                                                   int nbuck, int E) {
    __shared__ int buf[2][512];
    int t = threadIdx.x;
    int v = (t < nbuck) ? bhist[t] : 0;
    buf[0][t] = v;
    __syncthreads();
    int cur = 0;
    for (int off = 1; off < 512; off <<= 1) {
        int x = buf[cur][t];
        if (t >= off) x += buf[cur][t - off];
        buf[cur ^ 1][t] = x;
        cur ^= 1;
        __syncthreads();
    }
    int excl = (t == 0) ? 0 : buf[cur][t - 1];
    if (t < nbuck) {
        bbase[t] = excl;
        bcur_pad[t * 16] = excl;      // 64B-padded cursor (atomic target)
    }
    if (t == 0) bbase[nbuck] = E;
}

// ---------------- partition edges into bucket-segmented packed ebuf ---------
__global__ __launch_bounds__(256) void bucket_fill(const int* __restrict__ src,
                                                   const int* __restrict__ dst,
                                                   int* __restrict__ bcur_pad,
                                                   unsigned* __restrict__ ebuf, int E) {
    __shared__ int h[MAXBUCK];
    __shared__ int base[MAXBUCK];
    for (int i = threadIdx.x; i < MAXBUCK; i += 256) h[i] = 0;
    __syncthreads();
    int cbase = blockIdx.x * CHUNK;
    int lim   = min(cbase + CHUNK, E);
    for (int e = cbase + threadIdx.x; e < lim; e += 256)
        atomicAdd(&h[dst[e] >> BUCKET_SHIFT], 1);
    __syncthreads();
    for (int i = threadIdx.x; i < MAXBUCK; i += 256) {
        int c = h[i];
        base[i] = c ? atomicAdd(&bcur_pad[i * 16], c) : 0;
        h[i] = 0;
    }
    __syncthreads();
    for (int e = cbase + threadIdx.x; e < lim; e += 256) {
        int d = dst[e], b = d >> BUCKET_SHIFT;
        int r = atomicAdd(&h[b], 1);
        ebuf[base[b] + r] = ((unsigned)src[e] << BUCKET_SHIFT) | (unsigned)(d & (BUCKET_W - 1));
    }
}

// ---------------- fused CSR build: deg + local scan + rowptr/dinv + scatter --
// One block per bucket. rowptr[node] = bbase[k] + exclusive-prefix(deg in bucket)
// (global prefix is exact because bbase is the scanned bucket total).
__global__ __launch_bounds__(256) void csr_build(const unsigned* __restrict__ ebuf,
                                                 const int* __restrict__ bbase,
                                                 int* __restrict__ rowptr,
                                                 float* __restrict__ dinv,
                                                 int* __restrict__ csr,
                                                 int n, int E) {
    __shared__ int cnt[BUCKET_W];
    __shared__ int sbuf[2][BUCKET_W];
    __shared__ int lcur[BUCKET_W];
    int k = blockIdx.x, t = threadIdx.x;
    if (t < BUCKET_W) cnt[t] = 0;
    __syncthreads();
    int beg = bbase[k], end = bbase[k + 1];
    for (int e = beg + t; e < end; e += 256)
        atomicAdd(&cnt[ebuf[e] & (BUCKET_W - 1)], 1);
    __syncthreads();
    int myc = (t < BUCKET_W) ? cnt[t] : 0;
    if (t < BUCKET_W) sbuf[0][t] = myc;
    __syncthreads();
    int cur = 0;
    for (int off = 1; off < BUCKET_W; off <<= 1) {
        if (t < BUCKET_W) {
            int v = sbuf[cur][t];
            if (t >= off) v += sbuf[cur][t - off];
            sbuf[cur ^ 1][t] = v;
        }
        cur ^= 1;
        __syncthreads();
    }
    if (t < BUCKET_W) {
        int excl = sbuf[cur][t] - myc;          // exclusive prefix
        int base = beg + excl;
        lcur[t] = base;
        int node = (k << BUCKET_SHIFT) + t;
        if (node < n) {
            rowptr[node] = base;
            dinv[node]   = rsqrtf((float)(myc + 1));   // +1 self loop
        }
    }
    if (k == 0 && t == 0) rowptr[n] = E;
    __syncthreads();
    for (int e = beg + t; e < end; e += 256) {
        unsigned ed = ebuf[e];
        int pos = atomicAdd(&lcur[ed & (BUCKET_W - 1)], 1);
        csr[pos] = (int)(ed >> BUCKET_SHIFT);
    }
}

// ---------------- f16 MFMA GEMM: A in registers, B in LDS (staged once) ----
// Ch[M][BN]_f16 = dinv[row] * (A[M][K] @ W[K][BN]); WT is W^T f16 [BN][K].
// AT = float (layer 1) or _Float16 (layer 2).
template <int BN, int K, typename AT>
__global__ __launch_bounds__(256) void gemm_mfma(const AT* __restrict__ A,
                                                 const _Float16* __restrict__ WT,
                                                 const float* __restrict__ dinv,
                                                 _Float16* __restrict__ Ch, int M) {
    constexpr int NB = BN / 16;          // 8 or 4
    constexpr int CH = K / 32;           // k-chunks: 8 or 4
    constexpr int KP = K + 8;            // padded LDS row (f16)
    __shared__ _Float16 Bs[BN][KP];

    int tid  = threadIdx.x;
    int wave = tid >> 6, lane = tid & 63;
    int col  = lane & 15, kg = lane >> 4;
    int row0 = blockIdx.x * 64;
    int arow = row0 + wave * 16 + col;
    bool rowok = arow < M;

    // 1) issue ALL of this lane's A loads upfront
    float4 paf[sizeof(AT) == 4 ? 2 * CH : 1];
    f16x8  pah[sizeof(AT) == 2 ? CH : 1];
    const AT* Ab = A + (size_t)arow * K + kg * 8;
    if constexpr (sizeof(AT) == 4) {
#pragma unroll
        for (int c = 0; c < CH; ++c) {
            paf[2 * c]     = make_float4(0.f, 0.f, 0.f, 0.f);
            paf[2 * c + 1] = make_float4(0.f, 0.f, 0.f, 0.f);
            if (rowok) {
                paf[2 * c]     = *(const float4*)((const float*)Ab + c * 32);
                paf[2 * c + 1] = *(const float4*)((const float*)Ab + c * 32 + 4);
            }
        }
    } else {
#pragma unroll
        for (int c = 0; c < CH; ++c) {
            pah[c] = (f16x8){0, 0, 0, 0, 0, 0, 0, 0};
            if (rowok) pah[c] = *(const f16x8*)((const _Float16*)Ab + c * 32);
        }
    }

    // 2) stage WT -> LDS (padded rows), once
    constexpr int TOT = BN * K / 8;      // f16x8 units
#pragma unroll
    for (int l = 0; l < TOT / 256; ++l) {
        int u  = l * 256 + tid;
        int r  = u / (K / 8);
        int c8 = u % (K / 8);
        *(f16x8*)&Bs[r][c8 * 8] = *(const f16x8*)&WT[(size_t)r * K + c8 * 8];
    }
    __syncthreads();

    f32x4 acc[NB];
#pragma unroll
    for (int j = 0; j < NB; ++j) acc[j] = (f32x4){0.f, 0.f, 0.f, 0.f};

    // 3) k-loop: registers + LDS only
#pragma unroll
    for (int c = 0; c < CH; ++c) {
        f16x8 a;
        if constexpr (sizeof(AT) == 4) {
            float4 lo = paf[2 * c], hi = paf[2 * c + 1];
            a[0] = (_Float16)lo.x; a[1] = (_Float16)lo.y;
            a[2] = (_Float16)lo.z; a[3] = (_Float16)lo.w;
            a[4] = (_Float16)hi.x; a[5] = (_Float16)hi.y;
            a[6] = (_Float16)hi.z; a[7] = (_Float16)hi.w;
        } else {
            a = pah[c];
        }
#pragma unroll
        for (int j = 0; j < NB; ++j) {
            f16x8 b = *(const f16x8*)&Bs[j * 16 + col][c * 32 + kg * 8];
            acc[j] = __builtin_amdgcn_mfma_f32_16x16x32_f16(a, b, acc[j], 0, 0, 0);
        }
    }

    // epilogue: D row = wave*16 + kg*4 + r, col = j*16 + col
    int rbase = row0 + wave * 16 + kg * 4;
#pragma unroll
    for (int r = 0; r < 4; ++r) {
        int m = rbase + r;
        if (m < M) {
            float dv = dinv[m];
#pragma unroll
            for (int j = 0; j < NB; ++j)
                Ch[(size_t)m * BN + j * 16 + col] = (_Float16)(dv * acc[j][r]);
        }
    }
}

// ---------------- gather aggregation: f16 rows, f32 accumulate ----------------
// OutT = _Float16 (layer 1 -> X2 f16) or float (final output).
template <int F, bool RELU, typename OutT>
__global__ __launch_bounds__(256) void aggregate(const _Float16* __restrict__ Hs,
                                                 const int* __restrict__ rowptr,
                                                 const int* __restrict__ csr,
                                                 const float* __restrict__ dinv,
                                                 const float* __restrict__ bias,
                                                 OutT* __restrict__ out, int n) {
    constexpr int LPG = F / 4;                  // 32 (F=128) or 16 (F=64)
    int gid = (blockIdx.x * blockDim.x + threadIdx.x) / LPG;
    int sub = threadIdx.x & (LPG - 1);
    if (gid >= n) return;
    const int col = sub * 4;

    f16x4 h = *(const f16x4*)&Hs[(size_t)gid * F + col];
    float a0 = (float)h[0], a1 = (float)h[1], a2 = (float)h[2], a3 = (float)h[3];

    int beg = rowptr[gid], end = rowptr[gid + 1];
    int e = beg;

    for (; e + 8 <= end; e += 8) {
        int s0 = csr[e + 0], s1 = csr[e + 1], s2 = csr[e + 2], s3 = csr[e + 3];
        int s4 = csr[e + 4], s5 = csr[e + 5], s6 = csr[e + 6], s7 = csr[e + 7];
        f16x4 v0 = *(const f16x4*)&Hs[(size_t)s0 * F + col];
        f16x4 v1 = *(const f16x4*)&Hs[(size_t)s1 * F + col];
        f16x4 v2 = *(const f16x4*)&Hs[(size_t)s2 * F + col];
        f16x4 v3 = *(const f16x4*)&Hs[(size_t)s3 * F + col];
        f16x4 v4 = *(const f16x4*)&Hs[(size_t)s4 * F + col];
        f16x4 v5 = *(const f16x4*)&Hs[(size_t)s5 * F + col];
        f16x4 v6 = *(const f16x4*)&Hs[(size_t)s6 * F + col];
        f16x4 v7 = *(const f16x4*)&Hs[(size_t)s7 * F + col];
        a0 += (((float)v0[0] + (float)v1[0]) + ((float)v2[0] + (float)v3[0]))
            + (((float)v4[0] + (float)v5[0]) + ((float)v6[0] + (float)v7[0]));
        a1 += (((float)v0[1] + (float)v1[1]) + ((float)v2[1] + (float)v3[1]))
            + (((float)v4[1] + (float)v5[1]) + ((float)v6[1] + (float)v7[1]));
        a2 += (((float)v0[2] + (float)v1[2]) + ((float)v2[2] + (float)v3[2]))
            + (((float)v4[2] + (float)v5[2]) + ((float)v6[2] + (float)v7[2]));
        a3 += (((float)v0[3] + (float)v1[3]) + ((float)v2[3] + (float)v3[3]))
            + (((float)v4[3] + (float)v5[3]) + ((float)v6[3] + (float)v7[3]));
    }
    for (; e + 4 <= end; e += 4) {
        int s0 = csr[e + 0], s1 = csr[e + 1], s2 = csr[e + 2], s3 = csr[e + 3];
        f16x4 v0 = *(const f16x4*)&Hs[(size_t)s0 * F + col];
        f16x4 v1 = *(const f16x4*)&Hs[(size_t)s1 * F + col];
        f16x4 v2 = *(const f16x4*)&Hs[(size_t)s2 * F + col];
        f16x4 v3 = *(const f16x4*)&Hs[(size_t)s3 * F + col];
        a0 += ((float)v0[0] + (float)v1[0]) + ((float)v2[0] + (float)v3[0]);
        a1 += ((float)v0[1] + (float)v1[1]) + ((float)v2[1] + (float)v3[1]);
        a2 += ((float)v0[2] + (float)v1[2]) + ((float)v2[2] + (float)v3[2]);
        a3 += ((float)v0[3] + (float)v1[3]) + ((float)v2[3] + (float)v3[3]);
    }
    for (; e < end; ++e) {
        int s = csr[e];
        f16x4 v = *(const f16x4*)&Hs[(size_t)s * F + col];
        a0 += (float)v[0]; a1 += (float)v[1]; a2 += (float)v[2]; a3 += (float)v[3];
    }

    float dv = dinv[gid];
    float4 bb = *(const float4*)&bias[col];
    float o0 = dv * a0 + bb.x;
    float o1 = dv * a1 + bb.y;
    float o2 = dv * a2 + bb.z;
    float o3 = dv * a3 + bb.w;
    if (RELU) {
        o0 = fmaxf(o0, 0.f); o1 = fmaxf(o1, 0.f);
        o2 = fmaxf(o2, 0.f); o3 = fmaxf(o3, 0.f);
    }
    if constexpr (sizeof(OutT) == 2) {
        f16x4 ov;
        ov[0] = (_Float16)o0; ov[1] = (_Float16)o1;
        ov[2] = (_Float16)o2; ov[3] = (_Float16)o3;
        *(f16x4*)&out[(size_t)gid * F + col] = ov;
    } else {
        float4 ov = make_float4(o0, o1, o2, o3);
        *(float4*)&out[(size_t)gid * F + col] = ov;
    }
}

// ---------------- launch ----------------
extern "C" void kernel_launch(void* const* d_in, const int* in_sizes, int n_in,
                              void* d_out, int out_size, void* d_ws, size_t ws_size,
                              hipStream_t stream) {
    const float* x  = (const float*)d_in[0];
    const int*   ei = (const int*)d_in[1];
    const float* W1 = (const float*)d_in[2];
    const float* b1 = (const float*)d_in[3];
    const float* W2 = (const float*)d_in[4];
    const float* b2 = (const float*)d_in[5];
    float* out = (float*)d_out;

    const int N = in_sizes[0] / FIN;     // 50000
    const int E = in_sizes[1] / 2;       // 800000
    const int* src = ei;
    const int* dst = ei + E;

    char* w = (char*)d_ws;
    auto alloc = [&](size_t bytes) {
        void* p = (void*)w;
        w += (bytes + 255) & ~(size_t)255;
        return p;
    };
    float*    dinv     = (float*)alloc((size_t)N * 4);
    int*      rowptr   = (int*)alloc((size_t)(N + 1) * 4);
    int*      csr      = (int*)alloc((size_t)E * 4);
    int*      bhist    = (int*)alloc((size_t)MAXBUCK * 4);
    int*      bbase    = (int*)alloc((size_t)(MAXBUCK + 1) * 4);
    int*      bcur_pad = (int*)alloc((size_t)MAXBUCK * 16 * 4);
    unsigned* ebuf     = (unsigned*)alloc((size_t)E * 4);
    _Float16* WT1      = (_Float16*)alloc((size_t)FIN * F1 * 2);
    _Float16* WT2      = (_Float16*)alloc((size_t)F1 * F2 * 2);
    _Float16* Hs1      = (_Float16*)alloc((size_t)N * F1 * 2);  // reused as Hs2
    _Float16* X2h      = (_Float16*)alloc((size_t)N * F1 * 2);

    const int nbuck  = (N + BUCKET_W - 1) >> BUCKET_SHIFT;   // 391
    const int nchunk = (E + CHUNK - 1) / CHUNK;              // 98
    const int nprep  = 1 + (FIN * F1 + F1 * F2 + 255) / 256; // 1 + 160

    // ---- CSR build (bucketized, fused) ----
    prep<<<nprep, 256, 0, stream>>>(W1, W2, WT1, WT2, bhist);
    bucket_hist<<<nchunk, 256, 0, stream>>>(dst, bhist, E);
    scan_bucket<<<1, 512, 0, stream>>>(bhist, bbase, bcur_pad, nbuck, E);
    bucket_fill<<<nchunk, 256, 0, stream>>>(src, dst, bcur_pad, ebuf, E);
    csr_build<<<nbuck, 256, 0, stream>>>(ebuf, bbase, rowptr, dinv, csr, N, E);

    // layer 1: Hs1 = f16(dinv * (x @ W1)); X2h = f16(relu(dinv*(Hs1[v]+sum)+b1))
    gemm_mfma<F1, FIN, float><<<(N + 63) / 64, 256, 0, stream>>>(x, WT1, dinv, Hs1, N);
    {
        int blocks = (int)(((size_t)N * (F1 / 4) + 255) / 256);
        aggregate<F1, true, _Float16><<<blocks, 256, 0, stream>>>(Hs1, rowptr, csr, dinv, b1, X2h, N);
    }

    // layer 2: Hs2 = f16(dinv * (X2h @ W2)); out = dinv*(Hs2[v]+sum)+b2
    gemm_mfma<F2, F1, _Float16><<<(N + 63) / 64, 256, 0, stream>>>(X2h, WT2, dinv, Hs1, N);
    {
        int blocks = (int)(((size_t)N * (F2 / 4) + 255) / 256);
        aggregate<F2, false, float><<<blocks, 256, 0, stream>>>(Hs1, rowptr, csr, dinv, b2, out, N);
    }
}